// Round 7
// baseline (216.344 us; speedup 1.0000x reference)
//
#include <hip/hip_runtime.h>
#include <hip/hip_bf16.h>
#include <stdint.h>

// ============================================================================
// ImageManifoldHead on MI355X (gfx950) — round 7
//
// Pipeline (main path):
//   prep:   W_patch -> WpT bf16 [512][768]; W_out -> WoT bf16 [512][512]
//           manifold_prep: Wcsg bf16[16][512], We2g bf16[512][16]
//   patchify_bf16: images f32 -> Apat bf16 [25088][768]   (~BW roofline)
//   gemm1:  Apat @ WpT^T + b_patch + pos  -> x bf16
//   manifold_ln_v4: transposed-MFMA manifold + LN, in-place on x
//   gemm2:  x @ WoT^T + b_out -> out f32
//
// gemm_bf16 v4 — REGISTER-DIRECT, ZERO-LDS, ZERO-BARRIER:
//   MFMA fragment geometry is already coalesced as a global load (lanes
//   {l,l+16,l+32,l+48} cover one 64B line of a row). Load A/B frags straight
//   to VGPRs; intra-block redundancy (2x) hits L1; no staging latency on the
//   critical path; 4 waves/SIMD of pure TLP fill the MFMA pipe.
//   Round-5/6 lesson: the synchronous stage+vmcnt(0)+barrier skeleton forced
//   full DMA latency per K-step (12% MfmaUtil) — so remove the skeleton.
// ============================================================================

typedef __bf16 bf16_t;
typedef bf16_t bf16x8 __attribute__((ext_vector_type(8)));
typedef bf16_t bf16x4 __attribute__((ext_vector_type(4)));
typedef float  f32x4  __attribute__((ext_vector_type(4)));

#define IMG     448
#define PSZ     16
#define NHP     28
#define NPATCH  784
#define PDIM    768
#define DMODEL  512
#define MROWS   25088

__device__ __forceinline__ unsigned short bfbits(float v) {
  bf16_t h = (bf16_t)v;
  unsigned short u;
  __builtin_memcpy(&u, &h, 2);
  return u;
}
__device__ __forceinline__ float f_from_bits(unsigned u) {
  float f; __builtin_memcpy(&f, &u, 4); return f;
}

// ---------------------------------------------------------------------------
// prep: transpose f32 [K][N] -> bf16 [N][K]
// ---------------------------------------------------------------------------
__global__ __launch_bounds__(256) void transpose_to_bf16(
    const float* __restrict__ src, bf16_t* __restrict__ dst, int K, int N)
{
  __shared__ float t[64][65];
  const int tx = threadIdx.x;
  const int ty = threadIdx.y;
  const int bx = blockIdx.x * 64;
  const int by = blockIdx.y * 64;
  #pragma unroll
  for (int r = ty; r < 64; r += 4)
    t[r][tx] = src[(size_t)(by + r) * N + (bx + tx)];
  __syncthreads();
  #pragma unroll
  for (int r = ty; r < 64; r += 4)
    dst[(size_t)(bx + r) * K + (by + tx)] = (bf16_t)t[tx][r];
}

// ---------------------------------------------------------------------------
// manifold_prep:
//  Wcsg [16][512]: r<8: bf16(W_coord[n][r]); r 8-11: bf16(W_spinor[n][r-8]); else 0
//  We2g [512][16]: k<8: bf16(W_embed[k][n]); k==8: bf16(be[n]); else 0
// ---------------------------------------------------------------------------
__global__ __launch_bounds__(256) void manifold_prep(
    const float* __restrict__ Wc, const float* __restrict__ Ws,
    const float* __restrict__ We, const float* __restrict__ be,
    bf16_t* __restrict__ Wcsg, bf16_t* __restrict__ We2g)
{
  const int idx = blockIdx.x * 256 + threadIdx.x;   // grid 64 -> 16384
  if (idx < 8192) {
    const int r = idx >> 9, n = idx & 511;
    float v = 0.f;
    if (r < 8)       v = Wc[n * 8 + r];
    else if (r < 12) v = Ws[n * 4 + (r - 8)];
    Wcsg[idx] = (bf16_t)v;
  } else {
    const int j = idx - 8192;
    const int n = j >> 4, k = j & 15;
    float v = 0.f;
    if (k < 8)       v = We[k * 512 + n];
    else if (k == 8) v = be[n];
    We2g[j] = (bf16_t)v;
  }
}

// ---------------------------------------------------------------------------
// patchify_bf16: images (B,3,448,448) f32 -> Apat [25088][768] bf16
// ---------------------------------------------------------------------------
__global__ __launch_bounds__(256) void patchify_bf16(
    const float* __restrict__ images, bf16_t* __restrict__ Apat)
{
  __shared__ bf16_t t[16][456];
  const int tid = threadIdx.x;
  const int bid = blockIdx.x;
  const int b = bid / 84, rem = bid % 84;
  const int c = rem / 28, ph = rem % 28;
  const float* src = images + ((size_t)(b * 3 + c) * IMG + ph * PSZ) * IMG;

  #pragma unroll
  for (int idx = tid; idx < 16 * 112; idx += 256) {
    const int i = idx / 112, x4 = idx % 112;
    const float4 v = *(const float4*)(src + (size_t)i * IMG + x4 * 4);
    bf16x4 w;
    w[0] = (bf16_t)v.x; w[1] = (bf16_t)v.y; w[2] = (bf16_t)v.z; w[3] = (bf16_t)v.w;
    *(bf16x4*)&t[i][x4 * 4] = w;
  }
  __syncthreads();

  const size_t mbase = (size_t)b * NPATCH + (size_t)ph * NHP;
  #pragma unroll
  for (int idx = tid; idx < 28 * 64; idx += 256) {
    const int pw = idx >> 6, e = idx & 63;
    const int i = e >> 2, j4 = e & 3;
    const bf16x4 w = *(const bf16x4*)&t[i][pw * 16 + j4 * 4];
    *(bf16x4*)&Apat[(mbase + pw) * PDIM + c * 256 + i * 16 + j4 * 4] = w;
  }
}

// ---------------------------------------------------------------------------
// gemm v4 (register-direct, no LDS, no barriers):
//   C[M][512] = A[M][KDIM] @ BT[512][KDIM]^T
// EPI 0: out bf16, + bias + pos_embed[m%784]   EPI 1: out f32, + bias
// grid = 784 (1D), XCD-bijective swizzle (784 = 8*98)
// ---------------------------------------------------------------------------
template<int KDIM, int EPI>
__global__ __launch_bounds__(256, 4) void gemm_bf16(
    const bf16_t* __restrict__ A, const bf16_t* __restrict__ BT,
    const float* __restrict__ bias, const float* __restrict__ pos,
    void* __restrict__ outp)
{
  const int tid  = threadIdx.x;
  const int orig = blockIdx.x;
  const int wg   = (orig & 7) * 98 + (orig >> 3);   // XCD chunking, bijective
  const int n0   = (wg & 3) * 128;
  const int m0   = (wg >> 2) * 128;

  const int wave = tid >> 6, lane = tid & 63;
  const int wm = (wave >> 1) << 6;   // 0 / 64
  const int wn = (wave & 1) << 6;    // 0 / 64
  const int lr = lane & 15;
  const int lk = (lane >> 4) << 3;   // 0,8,16,24

  // per-fragment row pointers; k0 (bytes <= 1536) folds into offset imm
  const bf16_t* ap[4];
  const bf16_t* bp[4];
  #pragma unroll
  for (int i = 0; i < 4; ++i)
    ap[i] = A  + (size_t)(m0 + wm + i * 16 + lr) * KDIM + lk;
  #pragma unroll
  for (int j = 0; j < 4; ++j)
    bp[j] = BT + (size_t)(n0 + wn + j * 16 + lr) * KDIM + lk;

  f32x4 acc[4][4] = {};

  #pragma unroll 2
  for (int k0 = 0; k0 < KDIM; k0 += 32) {
    bf16x8 af[4], bfr[4];
    #pragma unroll
    for (int i = 0; i < 4; ++i) af[i]  = *(const bf16x8*)(ap[i] + k0);
    #pragma unroll
    for (int j = 0; j < 4; ++j) bfr[j] = *(const bf16x8*)(bp[j] + k0);
    #pragma unroll
    for (int i = 0; i < 4; ++i)
      #pragma unroll
      for (int j = 0; j < 4; ++j)
        acc[i][j] = __builtin_amdgcn_mfma_f32_16x16x32_bf16(af[i], bfr[j], acc[i][j], 0, 0, 0);
  }

  // C/D layout: col = lane&15 (n), row = (lane>>4)*4 + reg (m)
  const int q4 = (lane >> 4) << 2;
  const int colb = n0 + wn;
  #pragma unroll
  for (int i = 0; i < 4; ++i) {
    #pragma unroll
    for (int r = 0; r < 4; ++r) {
      const int mm = m0 + wm + i * 16 + q4 + r;
      if (EPI == 0) {
        const int pp = mm % NPATCH;
        const float* pe = pos + (size_t)pp * DMODEL;
        bf16_t* orow = (bf16_t*)outp + (size_t)mm * DMODEL;
        #pragma unroll
        for (int j = 0; j < 4; ++j) {
          const int nn = colb + j * 16 + lr;
          orow[nn] = (bf16_t)(acc[i][j][r] + bias[nn] + pe[nn]);
        }
      } else {
        float* orow = (float*)outp + (size_t)mm * DMODEL;
        #pragma unroll
        for (int j = 0; j < 4; ++j) {
          const int nn = colb + j * 16 + lr;
          orow[nn] = acc[i][j][r] + bias[nn];
        }
      }
    }
  }
}

// ---------------------------------------------------------------------------
// fallback gemm1 (fused patchify) — used only if ws too small
// ---------------------------------------------------------------------------
__global__ __launch_bounds__(256) void gemm1_fused_fallback(
    const float* __restrict__ images, const bf16_t* __restrict__ WpT,
    const float* __restrict__ b_patch, const float* __restrict__ pos_embed,
    bf16_t* __restrict__ xout)
{
  __shared__ bf16_t As[128][40];
  __shared__ bf16_t Bs[128][40];
  const int tid = threadIdx.x;
  const int n0 = blockIdx.x * 128;
  const int m0 = blockIdx.y * 128;
  const int sr = tid >> 1;
  const int sh = tid & 1;
  const int m  = m0 + sr;
  const int b  = m / NPATCH;
  const int p  = m - b * NPATCH;
  const int ph = p / NHP;
  const int pw = p - ph * NHP;
  const float* abase = images + (size_t)(b * 3) * (IMG * IMG)
                              + (size_t)(ph * PSZ) * IMG + pw * PSZ;
  const bf16_t* brow = WpT + (size_t)(n0 + sr) * PDIM + sh * 16;
  const int wave = tid >> 6;
  const int lane = tid & 63;
  const int wm = (wave >> 1) << 6;
  const int wn = (wave & 1) << 6;
  const int lr = lane & 15;
  const int lk = (lane >> 4) << 3;
  f32x4 acc[4][4] = {};
  for (int ks = 0; ks < PDIM / 32; ++ks) {
    const int k0 = ks * 32;
    const int c  = k0 >> 8;
    const int ib = (k0 >> 4) & 15;
    const float* asrc = abase + (size_t)c * (IMG * IMG) + (ib + sh) * IMG;
    const float4 av0 = *(const float4*)(asrc + 0);
    const float4 av1 = *(const float4*)(asrc + 4);
    const float4 av2 = *(const float4*)(asrc + 8);
    const float4 av3 = *(const float4*)(asrc + 12);
    const uint4 bv0 = *(const uint4*)(brow + k0);
    const uint4 bv1 = *(const uint4*)(brow + k0 + 8);
    __syncthreads();
    bf16x8 a0, a1;
    a0[0] = (bf16_t)av0.x; a0[1] = (bf16_t)av0.y; a0[2] = (bf16_t)av0.z; a0[3] = (bf16_t)av0.w;
    a0[4] = (bf16_t)av1.x; a0[5] = (bf16_t)av1.y; a0[6] = (bf16_t)av1.z; a0[7] = (bf16_t)av1.w;
    a1[0] = (bf16_t)av2.x; a1[1] = (bf16_t)av2.y; a1[2] = (bf16_t)av2.z; a1[3] = (bf16_t)av2.w;
    a1[4] = (bf16_t)av3.x; a1[5] = (bf16_t)av3.y; a1[6] = (bf16_t)av3.z; a1[7] = (bf16_t)av3.w;
    *(bf16x8*)&As[sr][sh * 16]     = a0;
    *(bf16x8*)&As[sr][sh * 16 + 8] = a1;
    *(uint4*)&Bs[sr][sh * 16]      = bv0;
    *(uint4*)&Bs[sr][sh * 16 + 8]  = bv1;
    __syncthreads();
    bf16x8 af[4], bfr[4];
    #pragma unroll
    for (int i = 0; i < 4; ++i) af[i]  = *(const bf16x8*)&As[wm + i * 16 + lr][lk];
    #pragma unroll
    for (int j = 0; j < 4; ++j) bfr[j] = *(const bf16x8*)&Bs[wn + j * 16 + lr][lk];
    #pragma unroll
    for (int i = 0; i < 4; ++i)
      #pragma unroll
      for (int j = 0; j < 4; ++j)
        acc[i][j] = __builtin_amdgcn_mfma_f32_16x16x32_bf16(af[i], bfr[j], acc[i][j], 0, 0, 0);
  }
  const int colb = n0 + wn;
  #pragma unroll
  for (int i = 0; i < 4; ++i) {
    #pragma unroll
    for (int r = 0; r < 4; ++r) {
      const int mm = m0 + wm + i * 16 + ((lane >> 4) << 2) + r;
      const int pp = mm % NPATCH;
      const float* pe = pos_embed + (size_t)pp * DMODEL;
      bf16_t* orow = xout + (size_t)mm * DMODEL;
      #pragma unroll
      for (int j = 0; j < 4; ++j) {
        const int nn = colb + j * 16 + lr;
        orow[nn] = (bf16_t)(acc[i][j][r] + b_patch[nn] + pe[nn]);
      }
    }
  }
}

// ---------------------------------------------------------------------------
// manifold_ln_v4: transposed-MFMA manifold + LayerNorm, in-place on x (bf16)
// ---------------------------------------------------------------------------
__global__ __launch_bounds__(256) void manifold_ln_v4(
    bf16_t* __restrict__ x,
    const bf16_t* __restrict__ Wcsg, const bf16_t* __restrict__ We2g,
    const float* __restrict__ b_coord, const float* __restrict__ b_spinor,
    const float* __restrict__ ln_gamma, const float* __restrict__ ln_beta)
{
  __shared__ bf16_t sWcs[16 * 512];   // [dc][k], XOR-swizzled: byte ^= (dc&7)<<4
  __shared__ bf16_t sWe2[512 * 16];   // [n][k],  XOR-swizzled: byte ^= (n&3)<<4
  __shared__ float  sg[512], sb[512];

  const int tid = threadIdx.x;

  #pragma unroll
  for (int i = 0; i < 4; ++i) {
    const int c = tid + 256 * i;
    const int r = c >> 6, off = (c & 63) * 16;
    const uint4 v = *(const uint4*)((const char*)Wcsg + (size_t)c * 16);
    *(uint4*)((char*)sWcs + ((r * 1024 + off) ^ ((r & 7) << 4))) = v;
  }
  #pragma unroll
  for (int i = 0; i < 4; ++i) {
    const int c = tid + 256 * i;
    const int n = c >> 1, half = (c & 1) * 16;
    const uint4 v = *(const uint4*)((const char*)We2g + (size_t)c * 16);
    *(uint4*)((char*)sWe2 + ((n * 32 + half) ^ ((n & 3) << 4))) = v;
  }
  for (int i = tid; i < 512; i += 256) {
    sg[i] = ln_gamma[i];
    sb[i] = ln_beta[i];
  }
  __syncthreads();

  const int w    = tid >> 6;
  const int lane = tid & 63;
  const int lr   = lane & 15;
  const int lk   = (lane >> 4) << 3;
  const int q4   = (lane >> 4) << 2;
  const int m0w  = blockIdx.x * 64 + w * 16;

  float bbv[4];
  #pragma unroll
  for (int r = 0; r < 4; ++r) {
    if (q4 == 0)      bbv[r] = b_coord[r];
    else if (q4 == 4) bbv[r] = b_coord[4 + r];
    else if (q4 == 8) bbv[r] = b_spinor[r];
    else              bbv[r] = 0.f;
  }

  const bf16_t* xrow = x + (size_t)(m0w + lr) * DMODEL + lk;
  f32x4 acc1 = {0.f, 0.f, 0.f, 0.f};
  #pragma unroll
  for (int ks = 0; ks < 16; ++ks) {
    const bf16x8 bf = *(const bf16x8*)(xrow + ks * 32);
    const int wb = (lr * 1024 + ks * 64 + lk * 2) ^ ((lr & 7) << 4);
    const bf16x8 wf = *(const bf16x8*)((const char*)sWcs + wb);
    acc1 = __builtin_amdgcn_mfma_f32_16x16x32_bf16(wf, bf, acc1, 0, 0, 0);
  }

  float sv[4];
  #pragma unroll
  for (int r = 0; r < 4; ++r) sv[r] = acc1[r] + bbv[r];

  const float k0own = sv[0] * sv[0] + sv[1] * sv[1] + sv[2] * sv[2] + sv[3] * sv[3];
  const float k0v = __shfl(k0own, 32 + lr, 64);

  float ov[4];
  #pragma unroll
  for (int r = 0; r < 4; ++r) ov[r] = __shfl_xor(sv[r], 16, 64);

  const bf16_t zb = (bf16_t)0.f;
  bf16x8 b2;
  if (lk == 0) {
    #pragma unroll
    for (int r = 0; r < 4; ++r) { b2[r] = (bf16_t)sv[r]; b2[4 + r] = (bf16_t)ov[r]; }
  } else if (lk == 8) {
    b2[0] = (bf16_t)1.0f;
    #pragma unroll
    for (int t = 1; t < 8; ++t) b2[t] = zb;
  } else {
    #pragma unroll
    for (int t = 0; t < 8; ++t) b2[t] = zb;
  }

  const bf16_t* xres = x + (size_t)(m0w + lr) * DMODEL + q4;
  unsigned xpA[32], xpB[32];
  float s1 = 0.f, s2 = 0.f;
  #pragma unroll
  for (int nf = 0; nf < 32; ++nf) {
    const int n = nf * 16 + lr;
    const int wb = (n * 32 + lk * 2) ^ ((n & 3) << 4);
    const bf16x8 wf = *(const bf16x8*)((const char*)sWe2 + wb);
    f32x4 acc2 = {0.f, 0.f, 0.f, 0.f};
    acc2 = __builtin_amdgcn_mfma_f32_16x16x32_bf16(wf, b2, acc2, 0, 0, 0);

    const bf16x4 xr = *(const bf16x4*)(xres + nf * 16);
    float xe[4];
    #pragma unroll
    for (int r = 0; r < 4; ++r) {
      xe[r] = acc2[r] * k0v + (float)xr[r];
      s1 += xe[r];
      s2 += xe[r] * xe[r];
    }
    xpA[nf] = (unsigned)bfbits(xe[0]) | ((unsigned)bfbits(xe[1]) << 16);
    xpB[nf] = (unsigned)bfbits(xe[2]) | ((unsigned)bfbits(xe[3]) << 16);
  }

  s1 += __shfl_xor(s1, 16, 64);
  s1 += __shfl_xor(s1, 32, 64);
  s2 += __shfl_xor(s2, 16, 64);
  s2 += __shfl_xor(s2, 32, 64);
  const float mu  = s1 * (1.f / 512.f);
  const float var = s2 * (1.f / 512.f) - mu * mu;
  const float rsg = rsqrtf(var + 1e-5f);

  bf16_t* xo = x + (size_t)(m0w + lr) * DMODEL + q4;
  #pragma unroll
  for (int nf = 0; nf < 32; ++nf) {
    const f32x4 g = *(const f32x4*)&sg[nf * 16 + q4];
    const f32x4 b = *(const f32x4*)&sb[nf * 16 + q4];
    const float v0 = f_from_bits(xpA[nf] << 16);
    const float v1 = f_from_bits(xpA[nf] & 0xffff0000u);
    const float v2 = f_from_bits(xpB[nf] << 16);
    const float v3 = f_from_bits(xpB[nf] & 0xffff0000u);
    bf16x4 o;
    o[0] = (bf16_t)((v0 - mu) * rsg * g[0] + b[0]);
    o[1] = (bf16_t)((v1 - mu) * rsg * g[1] + b[1]);
    o[2] = (bf16_t)((v2 - mu) * rsg * g[2] + b[2]);
    o[3] = (bf16_t)((v3 - mu) * rsg * g[3] + b[3]);
    *(bf16x4*)(xo + nf * 16) = o;
  }
}

// ---------------------------------------------------------------------------
extern "C" void kernel_launch(void* const* d_in, const int* in_sizes, int n_in,
                              void* d_out, int out_size, void* d_ws, size_t ws_size,
                              hipStream_t stream)
{
  const float* images    = (const float*)d_in[0];
  const float* W_patch   = (const float*)d_in[1];
  const float* b_patch   = (const float*)d_in[2];
  const float* pos_embed = (const float*)d_in[3];
  const float* W_coord   = (const float*)d_in[4];
  const float* b_coord   = (const float*)d_in[5];
  const float* W_spinor  = (const float*)d_in[6];
  const float* b_spinor  = (const float*)d_in[7];
  const float* W_embed   = (const float*)d_in[8];
  const float* b_embed   = (const float*)d_in[9];
  const float* ln_gamma  = (const float*)d_in[10];
  const float* ln_beta   = (const float*)d_in[11];
  const float* W_out     = (const float*)d_in[12];
  const float* b_out     = (const float*)d_in[13];
  float* out = (float*)d_out;

  const size_t SZ_APAT = (size_t)MROWS * PDIM * 2;     // 38,535,168
  const size_t SZ_X    = (size_t)MROWS * DMODEL * 2;   // 25,690,112
  const size_t SZ_WPT  = (size_t)DMODEL * PDIM * 2;    //    786,432
  const size_t SZ_WOT  = (size_t)DMODEL * DMODEL * 2;  //    524,288
  const size_t SZ_WCS  = 16 * 512 * 2;                 //     16,384
  const size_t SZ_WE2  = 512 * 16 * 2;                 //     16,384
  const size_t NEED_FULL = SZ_APAT + SZ_X + SZ_WPT + SZ_WOT + SZ_WCS + SZ_WE2;

  char* ws = (char*)d_ws;
  const bool full = (ws_size >= NEED_FULL);

  bf16_t *Apat, *x, *WpT, *WoT, *Wcsg, *We2g;
  if (full) {
    char* p = ws;
    Apat  = (bf16_t*)p;            p += SZ_APAT;
    x     = (bf16_t*)p;            p += SZ_X;
    WpT   = (bf16_t*)p;            p += SZ_WPT;
    WoT   = (bf16_t*)p;            p += SZ_WOT;
    Wcsg  = (bf16_t*)p;            p += SZ_WCS;
    We2g  = (bf16_t*)p;
  } else {
    char* p = ws;
    Apat  = nullptr;
    x     = (bf16_t*)p;            p += SZ_X;
    WpT   = (bf16_t*)p;            p += SZ_WPT;
    WoT   = (bf16_t*)p;            p += SZ_WOT;
    Wcsg  = (bf16_t*)p;            p += SZ_WCS;
    We2g  = (bf16_t*)p;
  }

  hipLaunchKernelGGL(transpose_to_bf16, dim3(8, 12), dim3(64, 4), 0, stream,
                     W_patch, WpT, PDIM, DMODEL);
  hipLaunchKernelGGL(transpose_to_bf16, dim3(8, 8), dim3(64, 4), 0, stream,
                     W_out, WoT, DMODEL, DMODEL);
  hipLaunchKernelGGL(manifold_prep, dim3(64), dim3(256), 0, stream,
                     W_coord, W_spinor, W_embed, b_embed, Wcsg, We2g);

  if (full) {
    hipLaunchKernelGGL(patchify_bf16, dim3(32 * 3 * 28), dim3(256), 0, stream,
                       images, Apat);
    hipLaunchKernelGGL((gemm_bf16<PDIM, 0>), dim3(784), dim3(256), 0, stream,
                       Apat, WpT, b_patch, pos_embed, (void*)x);
  } else {
    hipLaunchKernelGGL(gemm1_fused_fallback, dim3(4, 196), dim3(256), 0, stream,
                       images, WpT, b_patch, pos_embed, x);
  }

  hipLaunchKernelGGL(manifold_ln_v4, dim3(392), dim3(256), 0, stream,
                     x, Wcsg, We2g, b_coord, b_spinor, ln_gamma, ln_beta);

  hipLaunchKernelGGL((gemm_bf16<DMODEL, 1>), dim3(784), dim3(256), 0, stream,
                     x, WoT, b_out, (const float*)nullptr, (void*)out);
}

// Round 8
// 114.533 us; speedup vs baseline: 1.8889x; 1.8889x over previous
//
#include <hip/hip_runtime.h>
#include <hip/hip_bf16.h>
#include <stdint.h>

// ============================================================================
// ImageManifoldHead on MI355X (gfx950) — round 8
//
// Pipeline (main path):
//   prep:   W_patch -> WpT bf16 [512][768]; W_out -> WoT bf16 [512][512]
//           manifold_prep: Wcsg bf16[16][512], We2g bf16[512][16]
//   patchify_bf16: images f32 -> Apat bf16 [25088][768]   (~BW roofline)
//   gemm1:  Apat @ WpT^T + b_patch + pos  -> x bf16
//   manifold_ln_v4: transposed-MFMA manifold + LN, in-place on x
//   gemm2:  x @ WoT^T + b_out -> out f32
//
// gemm_bf16 v5 — occupancy-first: BM=64, BN=128, BK=64, 4 waves, 24 KB LDS.
//   grid = 1568 blocks (6.1 blocks/CU vs 3.06 before) -> 6 independent
//   barrier domains per CU hide the staging drain (R4-R7 invariant:
//   3 domains -> 12% MfmaUtil regardless of pipelining style).
//   Staging via global_load_lds w=16; chunk-XOR swizzle (row&7) applied on
//   BOTH sides (pre-swizzled global source + swizzled ds_read) -> <=2-way.
//   R7 lesson: register-direct doubles VMEM issue + thrashes L1 — reverted.
// ============================================================================

typedef __bf16 bf16_t;
typedef bf16_t bf16x8 __attribute__((ext_vector_type(8)));
typedef bf16_t bf16x4 __attribute__((ext_vector_type(4)));
typedef float  f32x4  __attribute__((ext_vector_type(4)));

#define IMG     448
#define PSZ     16
#define NHP     28
#define NPATCH  784
#define PDIM    768
#define DMODEL  512
#define MROWS   25088

__device__ __forceinline__ void gload16(void* lds, const void* g) {
  __builtin_amdgcn_global_load_lds(
      (__attribute__((address_space(1))) void*)(uintptr_t)g,
      (__attribute__((address_space(3))) void*)lds,
      16, 0, 0);
}

__device__ __forceinline__ unsigned short bfbits(float v) {
  bf16_t h = (bf16_t)v;
  unsigned short u;
  __builtin_memcpy(&u, &h, 2);
  return u;
}
__device__ __forceinline__ float f_from_bits(unsigned u) {
  float f; __builtin_memcpy(&f, &u, 4); return f;
}

// ---------------------------------------------------------------------------
// prep: transpose f32 [K][N] -> bf16 [N][K]
// ---------------------------------------------------------------------------
__global__ __launch_bounds__(256) void transpose_to_bf16(
    const float* __restrict__ src, bf16_t* __restrict__ dst, int K, int N)
{
  __shared__ float t[64][65];
  const int tx = threadIdx.x;
  const int ty = threadIdx.y;
  const int bx = blockIdx.x * 64;
  const int by = blockIdx.y * 64;
  #pragma unroll
  for (int r = ty; r < 64; r += 4)
    t[r][tx] = src[(size_t)(by + r) * N + (bx + tx)];
  __syncthreads();
  #pragma unroll
  for (int r = ty; r < 64; r += 4)
    dst[(size_t)(bx + r) * K + (by + tx)] = (bf16_t)t[tx][r];
}

// ---------------------------------------------------------------------------
// manifold_prep:
//  Wcsg [16][512]: r<8: bf16(W_coord[n][r]); r 8-11: bf16(W_spinor[n][r-8]); else 0
//  We2g [512][16]: k<8: bf16(W_embed[k][n]); k==8: bf16(be[n]); else 0
// ---------------------------------------------------------------------------
__global__ __launch_bounds__(256) void manifold_prep(
    const float* __restrict__ Wc, const float* __restrict__ Ws,
    const float* __restrict__ We, const float* __restrict__ be,
    bf16_t* __restrict__ Wcsg, bf16_t* __restrict__ We2g)
{
  const int idx = blockIdx.x * 256 + threadIdx.x;   // grid 64 -> 16384
  if (idx < 8192) {
    const int r = idx >> 9, n = idx & 511;
    float v = 0.f;
    if (r < 8)       v = Wc[n * 8 + r];
    else if (r < 12) v = Ws[n * 4 + (r - 8)];
    Wcsg[idx] = (bf16_t)v;
  } else {
    const int j = idx - 8192;
    const int n = j >> 4, k = j & 15;
    float v = 0.f;
    if (k < 8)       v = We[k * 512 + n];
    else if (k == 8) v = be[n];
    We2g[j] = (bf16_t)v;
  }
}

// ---------------------------------------------------------------------------
// patchify_bf16: images (B,3,448,448) f32 -> Apat [25088][768] bf16
// ---------------------------------------------------------------------------
__global__ __launch_bounds__(256) void patchify_bf16(
    const float* __restrict__ images, bf16_t* __restrict__ Apat)
{
  __shared__ bf16_t t[16][456];
  const int tid = threadIdx.x;
  const int bid = blockIdx.x;
  const int b = bid / 84, rem = bid % 84;
  const int c = rem / 28, ph = rem % 28;
  const float* src = images + ((size_t)(b * 3 + c) * IMG + ph * PSZ) * IMG;

  #pragma unroll
  for (int idx = tid; idx < 16 * 112; idx += 256) {
    const int i = idx / 112, x4 = idx % 112;
    const float4 v = *(const float4*)(src + (size_t)i * IMG + x4 * 4);
    bf16x4 w;
    w[0] = (bf16_t)v.x; w[1] = (bf16_t)v.y; w[2] = (bf16_t)v.z; w[3] = (bf16_t)v.w;
    *(bf16x4*)&t[i][x4 * 4] = w;
  }
  __syncthreads();

  const size_t mbase = (size_t)b * NPATCH + (size_t)ph * NHP;
  #pragma unroll
  for (int idx = tid; idx < 28 * 64; idx += 256) {
    const int pw = idx >> 6, e = idx & 63;
    const int i = e >> 2, j4 = e & 3;
    const bf16x4 w = *(const bf16x4*)&t[i][pw * 16 + j4 * 4];
    *(bf16x4*)&Apat[(mbase + pw) * PDIM + c * 256 + i * 16 + j4 * 4] = w;
  }
}

// ---------------------------------------------------------------------------
// gemm v5: C[M][512] = A[M][KDIM] @ BT[512][KDIM]^T
// BM=64, BN=128, BK=64, 4 waves (2x2 -> per-wave 32x64), 16x16x32 MFMA.
// EPI 0: out bf16, + bias + pos_embed[m%784]   EPI 1: out f32, + bias
// grid = (M/64)*(512/128) = 1568 (1D), XCD swizzle (1568 = 8*196)
// LDS chunk swizzle: LDS(row, q) holds global chunk q ^ (row&7); chunks=16B.
// ---------------------------------------------------------------------------
template<int KDIM, int EPI>
__global__ __launch_bounds__(256) void gemm_bf16(
    const bf16_t* __restrict__ A, const bf16_t* __restrict__ BT,
    const float* __restrict__ bias, const float* __restrict__ pos,
    void* __restrict__ outp)
{
  __shared__ bf16_t As[64 * 64];    //  8 KB
  __shared__ bf16_t Bs[128 * 64];   // 16 KB
  constexpr int NT = KDIM / 64;

  const int tid  = threadIdx.x;
  const int orig = blockIdx.x;
  const int wg   = (orig & 7) * 196 + (orig >> 3);   // bijective, 1568=8*196
  const int n0   = (wg & 3) * 128;
  const int m0   = (wg >> 2) * 64;

  const int wave = tid >> 6, lane = tid & 63;

  // staging: lane -> (row ra 0..7, global chunk ca = (lane&7) ^ ra)
  const int ra = lane >> 3;
  const int ca = (lane & 7) ^ ra;
  const bf16_t* ag = A  + (size_t)(m0 + wave * 8 + ra) * KDIM + ca * 8;
  const bf16_t* bg = BT + (size_t)(n0 + wave * 8 + ra) * KDIM + ca * 8;
  bf16_t* al0 = As + (wave * 8) * 64;
  bf16_t* al1 = As + (wave * 8 + 32) * 64;
  bf16_t* bl0 = Bs + (wave * 8) * 64;
  bf16_t* bl1 = Bs + (wave * 8 + 32) * 64;
  bf16_t* bl2 = Bs + (wave * 8 + 64) * 64;
  bf16_t* bl3 = Bs + (wave * 8 + 96) * 64;

  const int wm = (wave >> 1) * 32;   // 0 / 32
  const int wn = (wave & 1) * 64;    // 0 / 64
  const int lr = lane & 15;
  const int lt = lane >> 4;          // 0..3 (8-elem sub-chunk within 32-k)

  f32x4 acc[2][4] = {};

  for (int t = 0; t < NT; ++t) {
    const int k0 = t * 64;
    __syncthreads();                 // prev step's LDS reads complete
    gload16(al0, ag + k0);
    gload16(al1, ag + 32 * KDIM + k0);
    gload16(bl0, bg + k0);
    gload16(bl1, bg + 32 * KDIM + k0);
    gload16(bl2, bg + 64 * KDIM + k0);
    gload16(bl3, bg + 96 * KDIM + k0);
    __syncthreads();                 // implies vmcnt(0): DMA landed

    #pragma unroll
    for (int ks = 0; ks < 2; ++ks) {
      const int c = ks * 4 + lt;     // nominal chunk 0..7
      bf16x8 af[2], bfr[4];
      #pragma unroll
      for (int i = 0; i < 2; ++i) {
        const int row = wm + i * 16 + lr;
        af[i] = *(const bf16x8*)&As[row * 64 + ((c ^ (row & 7)) * 8)];
      }
      #pragma unroll
      for (int j = 0; j < 4; ++j) {
        const int row = wn + j * 16 + lr;
        bfr[j] = *(const bf16x8*)&Bs[row * 64 + ((c ^ (row & 7)) * 8)];
      }
      #pragma unroll
      for (int i = 0; i < 2; ++i)
        #pragma unroll
        for (int j = 0; j < 4; ++j)
          acc[i][j] = __builtin_amdgcn_mfma_f32_16x16x32_bf16(af[i], bfr[j], acc[i][j], 0, 0, 0);
    }
  }

  // C/D layout: col = lane&15 (n), row = (lane>>4)*4 + reg (m)
  const int q4 = lt << 2;
  const int colb = n0 + wn;
  #pragma unroll
  for (int i = 0; i < 2; ++i) {
    #pragma unroll
    for (int r = 0; r < 4; ++r) {
      const int mm = m0 + wm + i * 16 + q4 + r;
      if (EPI == 0) {
        const int pp = mm % NPATCH;
        const float* pe = pos + (size_t)pp * DMODEL;
        bf16_t* orow = (bf16_t*)outp + (size_t)mm * DMODEL;
        #pragma unroll
        for (int j = 0; j < 4; ++j) {
          const int nn = colb + j * 16 + lr;
          orow[nn] = (bf16_t)(acc[i][j][r] + bias[nn] + pe[nn]);
        }
      } else {
        float* orow = (float*)outp + (size_t)mm * DMODEL;
        #pragma unroll
        for (int j = 0; j < 4; ++j) {
          const int nn = colb + j * 16 + lr;
          orow[nn] = acc[i][j][r] + bias[nn];
        }
      }
    }
  }
}

// ---------------------------------------------------------------------------
// fallback gemm1 (fused patchify) — used only if ws too small
// ---------------------------------------------------------------------------
__global__ __launch_bounds__(256) void gemm1_fused_fallback(
    const float* __restrict__ images, const bf16_t* __restrict__ WpT,
    const float* __restrict__ b_patch, const float* __restrict__ pos_embed,
    bf16_t* __restrict__ xout)
{
  __shared__ bf16_t As[128][40];
  __shared__ bf16_t Bs[128][40];
  const int tid = threadIdx.x;
  const int n0 = blockIdx.x * 128;
  const int m0 = blockIdx.y * 128;
  const int sr = tid >> 1;
  const int sh = tid & 1;
  const int m  = m0 + sr;
  const int b  = m / NPATCH;
  const int p  = m - b * NPATCH;
  const int ph = p / NHP;
  const int pw = p - ph * NHP;
  const float* abase = images + (size_t)(b * 3) * (IMG * IMG)
                              + (size_t)(ph * PSZ) * IMG + pw * PSZ;
  const bf16_t* brow = WpT + (size_t)(n0 + sr) * PDIM + sh * 16;
  const int wave = tid >> 6;
  const int lane = tid & 63;
  const int wm = (wave >> 1) << 6;
  const int wn = (wave & 1) << 6;
  const int lr = lane & 15;
  const int lk = (lane >> 4) << 3;
  f32x4 acc[4][4] = {};
  for (int ks = 0; ks < PDIM / 32; ++ks) {
    const int k0 = ks * 32;
    const int c  = k0 >> 8;
    const int ib = (k0 >> 4) & 15;
    const float* asrc = abase + (size_t)c * (IMG * IMG) + (ib + sh) * IMG;
    const float4 av0 = *(const float4*)(asrc + 0);
    const float4 av1 = *(const float4*)(asrc + 4);
    const float4 av2 = *(const float4*)(asrc + 8);
    const float4 av3 = *(const float4*)(asrc + 12);
    const uint4 bv0 = *(const uint4*)(brow + k0);
    const uint4 bv1 = *(const uint4*)(brow + k0 + 8);
    __syncthreads();
    bf16x8 a0, a1;
    a0[0] = (bf16_t)av0.x; a0[1] = (bf16_t)av0.y; a0[2] = (bf16_t)av0.z; a0[3] = (bf16_t)av0.w;
    a0[4] = (bf16_t)av1.x; a0[5] = (bf16_t)av1.y; a0[6] = (bf16_t)av1.z; a0[7] = (bf16_t)av1.w;
    a1[0] = (bf16_t)av2.x; a1[1] = (bf16_t)av2.y; a1[2] = (bf16_t)av2.z; a1[3] = (bf16_t)av2.w;
    a1[4] = (bf16_t)av3.x; a1[5] = (bf16_t)av3.y; a1[6] = (bf16_t)av3.z; a1[7] = (bf16_t)av3.w;
    *(bf16x8*)&As[sr][sh * 16]     = a0;
    *(bf16x8*)&As[sr][sh * 16 + 8] = a1;
    *(uint4*)&Bs[sr][sh * 16]      = bv0;
    *(uint4*)&Bs[sr][sh * 16 + 8]  = bv1;
    __syncthreads();
    bf16x8 af[4], bfr[4];
    #pragma unroll
    for (int i = 0; i < 4; ++i) af[i]  = *(const bf16x8*)&As[wm + i * 16 + lr][lk];
    #pragma unroll
    for (int j = 0; j < 4; ++j) bfr[j] = *(const bf16x8*)&Bs[wn + j * 16 + lr][lk];
    #pragma unroll
    for (int i = 0; i < 4; ++i)
      #pragma unroll
      for (int j = 0; j < 4; ++j)
        acc[i][j] = __builtin_amdgcn_mfma_f32_16x16x32_bf16(af[i], bfr[j], acc[i][j], 0, 0, 0);
  }
  const int colb = n0 + wn;
  #pragma unroll
  for (int i = 0; i < 4; ++i) {
    #pragma unroll
    for (int r = 0; r < 4; ++r) {
      const int mm = m0 + wm + i * 16 + ((lane >> 4) << 2) + r;
      const int pp = mm % NPATCH;
      const float* pe = pos_embed + (size_t)pp * DMODEL;
      bf16_t* orow = xout + (size_t)mm * DMODEL;
      #pragma unroll
      for (int j = 0; j < 4; ++j) {
        const int nn = colb + j * 16 + lr;
        orow[nn] = (bf16_t)(acc[i][j][r] + b_patch[nn] + pe[nn]);
      }
    }
  }
}

// ---------------------------------------------------------------------------
// manifold_ln_v4: transposed-MFMA manifold + LayerNorm, in-place on x (bf16)
// ---------------------------------------------------------------------------
__global__ __launch_bounds__(256) void manifold_ln_v4(
    bf16_t* __restrict__ x,
    const bf16_t* __restrict__ Wcsg, const bf16_t* __restrict__ We2g,
    const float* __restrict__ b_coord, const float* __restrict__ b_spinor,
    const float* __restrict__ ln_gamma, const float* __restrict__ ln_beta)
{
  __shared__ bf16_t sWcs[16 * 512];   // [dc][k], XOR-swizzled: byte ^= (dc&7)<<4
  __shared__ bf16_t sWe2[512 * 16];   // [n][k],  XOR-swizzled: byte ^= (n&3)<<4
  __shared__ float  sg[512], sb[512];

  const int tid = threadIdx.x;

  #pragma unroll
  for (int i = 0; i < 4; ++i) {
    const int c = tid + 256 * i;
    const int r = c >> 6, off = (c & 63) * 16;
    const uint4 v = *(const uint4*)((const char*)Wcsg + (size_t)c * 16);
    *(uint4*)((char*)sWcs + ((r * 1024 + off) ^ ((r & 7) << 4))) = v;
  }
  #pragma unroll
  for (int i = 0; i < 4; ++i) {
    const int c = tid + 256 * i;
    const int n = c >> 1, half = (c & 1) * 16;
    const uint4 v = *(const uint4*)((const char*)We2g + (size_t)c * 16);
    *(uint4*)((char*)sWe2 + ((n * 32 + half) ^ ((n & 3) << 4))) = v;
  }
  for (int i = tid; i < 512; i += 256) {
    sg[i] = ln_gamma[i];
    sb[i] = ln_beta[i];
  }
  __syncthreads();

  const int w    = tid >> 6;
  const int lane = tid & 63;
  const int lr   = lane & 15;
  const int lk   = (lane >> 4) << 3;
  const int q4   = (lane >> 4) << 2;
  const int m0w  = blockIdx.x * 64 + w * 16;

  float bbv[4];
  #pragma unroll
  for (int r = 0; r < 4; ++r) {
    if (q4 == 0)      bbv[r] = b_coord[r];
    else if (q4 == 4) bbv[r] = b_coord[4 + r];
    else if (q4 == 8) bbv[r] = b_spinor[r];
    else              bbv[r] = 0.f;
  }

  const bf16_t* xrow = x + (size_t)(m0w + lr) * DMODEL + lk;
  f32x4 acc1 = {0.f, 0.f, 0.f, 0.f};
  #pragma unroll
  for (int ks = 0; ks < 16; ++ks) {
    const bf16x8 bf = *(const bf16x8*)(xrow + ks * 32);
    const int wb = (lr * 1024 + ks * 64 + lk * 2) ^ ((lr & 7) << 4);
    const bf16x8 wf = *(const bf16x8*)((const char*)sWcs + wb);
    acc1 = __builtin_amdgcn_mfma_f32_16x16x32_bf16(wf, bf, acc1, 0, 0, 0);
  }

  float sv[4];
  #pragma unroll
  for (int r = 0; r < 4; ++r) sv[r] = acc1[r] + bbv[r];

  const float k0own = sv[0] * sv[0] + sv[1] * sv[1] + sv[2] * sv[2] + sv[3] * sv[3];
  const float k0v = __shfl(k0own, 32 + lr, 64);

  float ov[4];
  #pragma unroll
  for (int r = 0; r < 4; ++r) ov[r] = __shfl_xor(sv[r], 16, 64);

  const bf16_t zb = (bf16_t)0.f;
  bf16x8 b2;
  if (lk == 0) {
    #pragma unroll
    for (int r = 0; r < 4; ++r) { b2[r] = (bf16_t)sv[r]; b2[4 + r] = (bf16_t)ov[r]; }
  } else if (lk == 8) {
    b2[0] = (bf16_t)1.0f;
    #pragma unroll
    for (int t = 1; t < 8; ++t) b2[t] = zb;
  } else {
    #pragma unroll
    for (int t = 0; t < 8; ++t) b2[t] = zb;
  }

  const bf16_t* xres = x + (size_t)(m0w + lr) * DMODEL + q4;
  unsigned xpA[32], xpB[32];
  float s1 = 0.f, s2 = 0.f;
  #pragma unroll
  for (int nf = 0; nf < 32; ++nf) {
    const int n = nf * 16 + lr;
    const int wb = (n * 32 + lk * 2) ^ ((n & 3) << 4);
    const bf16x8 wf = *(const bf16x8*)((const char*)sWe2 + wb);
    f32x4 acc2 = {0.f, 0.f, 0.f, 0.f};
    acc2 = __builtin_amdgcn_mfma_f32_16x16x32_bf16(wf, b2, acc2, 0, 0, 0);

    const bf16x4 xr = *(const bf16x4*)(xres + nf * 16);
    float xe[4];
    #pragma unroll
    for (int r = 0; r < 4; ++r) {
      xe[r] = acc2[r] * k0v + (float)xr[r];
      s1 += xe[r];
      s2 += xe[r] * xe[r];
    }
    xpA[nf] = (unsigned)bfbits(xe[0]) | ((unsigned)bfbits(xe[1]) << 16);
    xpB[nf] = (unsigned)bfbits(xe[2]) | ((unsigned)bfbits(xe[3]) << 16);
  }

  s1 += __shfl_xor(s1, 16, 64);
  s1 += __shfl_xor(s1, 32, 64);
  s2 += __shfl_xor(s2, 16, 64);
  s2 += __shfl_xor(s2, 32, 64);
  const float mu  = s1 * (1.f / 512.f);
  const float var = s2 * (1.f / 512.f) - mu * mu;
  const float rsg = rsqrtf(var + 1e-5f);

  bf16_t* xo = x + (size_t)(m0w + lr) * DMODEL + q4;
  #pragma unroll
  for (int nf = 0; nf < 32; ++nf) {
    const f32x4 g = *(const f32x4*)&sg[nf * 16 + q4];
    const f32x4 b = *(const f32x4*)&sb[nf * 16 + q4];
    const float v0 = f_from_bits(xpA[nf] << 16);
    const float v1 = f_from_bits(xpA[nf] & 0xffff0000u);
    const float v2 = f_from_bits(xpB[nf] << 16);
    const float v3 = f_from_bits(xpB[nf] & 0xffff0000u);
    bf16x4 o;
    o[0] = (bf16_t)((v0 - mu) * rsg * g[0] + b[0]);
    o[1] = (bf16_t)((v1 - mu) * rsg * g[1] + b[1]);
    o[2] = (bf16_t)((v2 - mu) * rsg * g[2] + b[2]);
    o[3] = (bf16_t)((v3 - mu) * rsg * g[3] + b[3]);
    *(bf16x4*)(xo + nf * 16) = o;
  }
}

// ---------------------------------------------------------------------------
extern "C" void kernel_launch(void* const* d_in, const int* in_sizes, int n_in,
                              void* d_out, int out_size, void* d_ws, size_t ws_size,
                              hipStream_t stream)
{
  const float* images    = (const float*)d_in[0];
  const float* W_patch   = (const float*)d_in[1];
  const float* b_patch   = (const float*)d_in[2];
  const float* pos_embed = (const float*)d_in[3];
  const float* W_coord   = (const float*)d_in[4];
  const float* b_coord   = (const float*)d_in[5];
  const float* W_spinor  = (const float*)d_in[6];
  const float* b_spinor  = (const float*)d_in[7];
  const float* W_embed   = (const float*)d_in[8];
  const float* b_embed   = (const float*)d_in[9];
  const float* ln_gamma  = (const float*)d_in[10];
  const float* ln_beta   = (const float*)d_in[11];
  const float* W_out     = (const float*)d_in[12];
  const float* b_out     = (const float*)d_in[13];
  float* out = (float*)d_out;

  const size_t SZ_APAT = (size_t)MROWS * PDIM * 2;     // 38,535,168
  const size_t SZ_X    = (size_t)MROWS * DMODEL * 2;   // 25,690,112
  const size_t SZ_WPT  = (size_t)DMODEL * PDIM * 2;    //    786,432
  const size_t SZ_WOT  = (size_t)DMODEL * DMODEL * 2;  //    524,288
  const size_t SZ_WCS  = 16 * 512 * 2;                 //     16,384
  const size_t SZ_WE2  = 512 * 16 * 2;                 //     16,384
  const size_t NEED_FULL = SZ_APAT + SZ_X + SZ_WPT + SZ_WOT + SZ_WCS + SZ_WE2;

  char* ws = (char*)d_ws;
  const bool full = (ws_size >= NEED_FULL);

  bf16_t *Apat, *x, *WpT, *WoT, *Wcsg, *We2g;
  if (full) {
    char* p = ws;
    Apat  = (bf16_t*)p;            p += SZ_APAT;
    x     = (bf16_t*)p;            p += SZ_X;
    WpT   = (bf16_t*)p;            p += SZ_WPT;
    WoT   = (bf16_t*)p;            p += SZ_WOT;
    Wcsg  = (bf16_t*)p;            p += SZ_WCS;
    We2g  = (bf16_t*)p;
  } else {
    char* p = ws;
    Apat  = nullptr;
    x     = (bf16_t*)p;            p += SZ_X;
    WpT   = (bf16_t*)p;            p += SZ_WPT;
    WoT   = (bf16_t*)p;            p += SZ_WOT;
    Wcsg  = (bf16_t*)p;            p += SZ_WCS;
    We2g  = (bf16_t*)p;
  }

  hipLaunchKernelGGL(transpose_to_bf16, dim3(8, 12), dim3(64, 4), 0, stream,
                     W_patch, WpT, PDIM, DMODEL);
  hipLaunchKernelGGL(transpose_to_bf16, dim3(8, 8), dim3(64, 4), 0, stream,
                     W_out, WoT, DMODEL, DMODEL);
  hipLaunchKernelGGL(manifold_prep, dim3(64), dim3(256), 0, stream,
                     W_coord, W_spinor, W_embed, b_embed, Wcsg, We2g);

  if (full) {
    hipLaunchKernelGGL(patchify_bf16, dim3(32 * 3 * 28), dim3(256), 0, stream,
                       images, Apat);
    hipLaunchKernelGGL((gemm_bf16<PDIM, 0>), dim3(1568), dim3(256), 0, stream,
                       Apat, WpT, b_patch, pos_embed, (void*)x);
  } else {
    hipLaunchKernelGGL(gemm1_fused_fallback, dim3(4, 196), dim3(256), 0, stream,
                       images, WpT, b_patch, pos_embed, x);
  }

  hipLaunchKernelGGL(manifold_ln_v4, dim3(392), dim3(256), 0, stream,
                     x, Wcsg, We2g, b_coord, b_spinor, ln_gamma, ln_beta);

  hipLaunchKernelGGL((gemm_bf16<DMODEL, 1>), dim3(1568), dim3(256), 0, stream,
                     x, WoT, b_out, (const float*)nullptr, (void*)out);
}

// Round 9
// 112.554 us; speedup vs baseline: 1.9221x; 1.0176x over previous
//
#include <hip/hip_runtime.h>
#include <hip/hip_bf16.h>
#include <stdint.h>

// ============================================================================
// ImageManifoldHead on MI355X (gfx950) — round 9
//
// Pipeline (main path):
//   prep:   W_patch -> WpT bf16 [512][768]; W_out -> WoT bf16 [512][512]
//           manifold_prep: Wcsg bf16[16][512] (Wc rows 0-7 | Ws rows 8-11 | 0)
//   patchify_bf16: images f32 -> Apat bf16 [25088][768]
//   gemm1:  Apat @ WpT^T + b_patch + pos  -> x bf16        (v5 structure)
//   coords_k0: x @ Wcs^T (MFMA, weights from L1) -> Cbuf[row][12] (c0-7, K0)
//   embed_ln:  x = LN((c@We + be)*K0 + x) — VALU, reg-staged weights, in-place
//   gemm2:  x @ WoT^T + b_out -> out f32                   (v5 structure)
//
// R8 lesson: manifold_ln_v4 was latency-bound (1.5 blocks/CU, serial
// phase1->phase2 chain, 8.6% occupancy). Split into two streaming kernels:
// K1 = 1568 independent 1-wave blocks, no LDS/barriers; K2 = 3136 waves,
// rank-8 embed on VALU with weights in registers.
// ============================================================================

typedef __bf16 bf16_t;
typedef bf16_t bf16x8 __attribute__((ext_vector_type(8)));
typedef bf16_t bf16x4 __attribute__((ext_vector_type(4)));
typedef float  f32x4  __attribute__((ext_vector_type(4)));

#define IMG     448
#define PSZ     16
#define NHP     28
#define NPATCH  784
#define PDIM    768
#define DMODEL  512
#define MROWS   25088

__device__ __forceinline__ void gload16(void* lds, const void* g) {
  __builtin_amdgcn_global_load_lds(
      (__attribute__((address_space(1))) void*)(uintptr_t)g,
      (__attribute__((address_space(3))) void*)lds,
      16, 0, 0);
}

// ---------------------------------------------------------------------------
// prep: transpose f32 [K][N] -> bf16 [N][K]
// ---------------------------------------------------------------------------
__global__ __launch_bounds__(256) void transpose_to_bf16(
    const float* __restrict__ src, bf16_t* __restrict__ dst, int K, int N)
{
  __shared__ float t[64][65];
  const int tx = threadIdx.x;
  const int ty = threadIdx.y;
  const int bx = blockIdx.x * 64;
  const int by = blockIdx.y * 64;
  #pragma unroll
  for (int r = ty; r < 64; r += 4)
    t[r][tx] = src[(size_t)(by + r) * N + (bx + tx)];
  __syncthreads();
  #pragma unroll
  for (int r = ty; r < 64; r += 4)
    dst[(size_t)(bx + r) * K + (by + tx)] = (bf16_t)t[tx][r];
}

// ---------------------------------------------------------------------------
// manifold_prep:
//  Wcsg [16][512]: r<8: bf16(W_coord[n][r]); r 8-11: bf16(W_spinor[n][r-8]); else 0
// ---------------------------------------------------------------------------
__global__ __launch_bounds__(256) void manifold_prep(
    const float* __restrict__ Wc, const float* __restrict__ Ws,
    bf16_t* __restrict__ Wcsg)
{
  const int idx = blockIdx.x * 256 + threadIdx.x;   // grid 32 -> 8192
  if (idx < 8192) {
    const int r = idx >> 9, n = idx & 511;
    float v = 0.f;
    if (r < 8)       v = Wc[n * 8 + r];
    else if (r < 12) v = Ws[n * 4 + (r - 8)];
    Wcsg[idx] = (bf16_t)v;
  }
}

// ---------------------------------------------------------------------------
// patchify_bf16: images (B,3,448,448) f32 -> Apat [25088][768] bf16
// ---------------------------------------------------------------------------
__global__ __launch_bounds__(256) void patchify_bf16(
    const float* __restrict__ images, bf16_t* __restrict__ Apat)
{
  __shared__ bf16_t t[16][456];
  const int tid = threadIdx.x;
  const int bid = blockIdx.x;
  const int b = bid / 84, rem = bid % 84;
  const int c = rem / 28, ph = rem % 28;
  const float* src = images + ((size_t)(b * 3 + c) * IMG + ph * PSZ) * IMG;

  #pragma unroll
  for (int idx = tid; idx < 16 * 112; idx += 256) {
    const int i = idx / 112, x4 = idx % 112;
    const float4 v = *(const float4*)(src + (size_t)i * IMG + x4 * 4);
    bf16x4 w;
    w[0] = (bf16_t)v.x; w[1] = (bf16_t)v.y; w[2] = (bf16_t)v.z; w[3] = (bf16_t)v.w;
    *(bf16x4*)&t[i][x4 * 4] = w;
  }
  __syncthreads();

  const size_t mbase = (size_t)b * NPATCH + (size_t)ph * NHP;
  #pragma unroll
  for (int idx = tid; idx < 28 * 64; idx += 256) {
    const int pw = idx >> 6, e = idx & 63;
    const int i = e >> 2, j4 = e & 3;
    const bf16x4 w = *(const bf16x4*)&t[i][pw * 16 + j4 * 4];
    *(bf16x4*)&Apat[(mbase + pw) * PDIM + c * 256 + i * 16 + j4 * 4] = w;
  }
}

// ---------------------------------------------------------------------------
// gemm v5: C[M][512] = A[M][KDIM] @ BT[512][KDIM]^T
// BM=64, BN=128, BK=64, 4 waves (per-wave 32x64), 16x16x32 MFMA.
// grid = 1568 (1D), XCD swizzle; chunk-XOR LDS swizzle both sides.
// ---------------------------------------------------------------------------
template<int KDIM, int EPI>
__global__ __launch_bounds__(256) void gemm_bf16(
    const bf16_t* __restrict__ A, const bf16_t* __restrict__ BT,
    const float* __restrict__ bias, const float* __restrict__ pos,
    void* __restrict__ outp)
{
  __shared__ bf16_t As[64 * 64];    //  8 KB
  __shared__ bf16_t Bs[128 * 64];   // 16 KB
  constexpr int NT = KDIM / 64;

  const int tid  = threadIdx.x;
  const int orig = blockIdx.x;
  const int wg   = (orig & 7) * 196 + (orig >> 3);   // bijective, 1568=8*196
  const int n0   = (wg & 3) * 128;
  const int m0   = (wg >> 2) * 64;

  const int wave = tid >> 6, lane = tid & 63;

  const int ra = lane >> 3;
  const int ca = (lane & 7) ^ ra;
  const bf16_t* ag = A  + (size_t)(m0 + wave * 8 + ra) * KDIM + ca * 8;
  const bf16_t* bg = BT + (size_t)(n0 + wave * 8 + ra) * KDIM + ca * 8;
  bf16_t* al0 = As + (wave * 8) * 64;
  bf16_t* al1 = As + (wave * 8 + 32) * 64;
  bf16_t* bl0 = Bs + (wave * 8) * 64;
  bf16_t* bl1 = Bs + (wave * 8 + 32) * 64;
  bf16_t* bl2 = Bs + (wave * 8 + 64) * 64;
  bf16_t* bl3 = Bs + (wave * 8 + 96) * 64;

  const int wm = (wave >> 1) * 32;
  const int wn = (wave & 1) * 64;
  const int lr = lane & 15;
  const int lt = lane >> 4;

  f32x4 acc[2][4] = {};

  for (int t = 0; t < NT; ++t) {
    const int k0 = t * 64;
    __syncthreads();
    gload16(al0, ag + k0);
    gload16(al1, ag + 32 * KDIM + k0);
    gload16(bl0, bg + k0);
    gload16(bl1, bg + 32 * KDIM + k0);
    gload16(bl2, bg + 64 * KDIM + k0);
    gload16(bl3, bg + 96 * KDIM + k0);
    __syncthreads();

    #pragma unroll
    for (int ks = 0; ks < 2; ++ks) {
      const int c = ks * 4 + lt;
      bf16x8 af[2], bfr[4];
      #pragma unroll
      for (int i = 0; i < 2; ++i) {
        const int row = wm + i * 16 + lr;
        af[i] = *(const bf16x8*)&As[row * 64 + ((c ^ (row & 7)) * 8)];
      }
      #pragma unroll
      for (int j = 0; j < 4; ++j) {
        const int row = wn + j * 16 + lr;
        bfr[j] = *(const bf16x8*)&Bs[row * 64 + ((c ^ (row & 7)) * 8)];
      }
      #pragma unroll
      for (int i = 0; i < 2; ++i)
        #pragma unroll
        for (int j = 0; j < 4; ++j)
          acc[i][j] = __builtin_amdgcn_mfma_f32_16x16x32_bf16(af[i], bfr[j], acc[i][j], 0, 0, 0);
    }
  }

  const int q4 = lt << 2;
  const int colb = n0 + wn;
  #pragma unroll
  for (int i = 0; i < 2; ++i) {
    #pragma unroll
    for (int r = 0; r < 4; ++r) {
      const int mm = m0 + wm + i * 16 + q4 + r;
      if (EPI == 0) {
        const int pp = mm % NPATCH;
        const float* pe = pos + (size_t)pp * DMODEL;
        bf16_t* orow = (bf16_t*)outp + (size_t)mm * DMODEL;
        #pragma unroll
        for (int j = 0; j < 4; ++j) {
          const int nn = colb + j * 16 + lr;
          orow[nn] = (bf16_t)(acc[i][j][r] + bias[nn] + pe[nn]);
        }
      } else {
        float* orow = (float*)outp + (size_t)mm * DMODEL;
        #pragma unroll
        for (int j = 0; j < 4; ++j) {
          const int nn = colb + j * 16 + lr;
          orow[nn] = acc[i][j][r] + bias[nn];
        }
      }
    }
  }
}

// ---------------------------------------------------------------------------
// fallback gemm1 (fused patchify) — used only if ws too small
// ---------------------------------------------------------------------------
__global__ __launch_bounds__(256) void gemm1_fused_fallback(
    const float* __restrict__ images, const bf16_t* __restrict__ WpT,
    const float* __restrict__ b_patch, const float* __restrict__ pos_embed,
    bf16_t* __restrict__ xout)
{
  __shared__ bf16_t As[128][40];
  __shared__ bf16_t Bs[128][40];
  const int tid = threadIdx.x;
  const int n0 = blockIdx.x * 128;
  const int m0 = blockIdx.y * 128;
  const int sr = tid >> 1;
  const int sh = tid & 1;
  const int m  = m0 + sr;
  const int b  = m / NPATCH;
  const int p  = m - b * NPATCH;
  const int ph = p / NHP;
  const int pw = p - ph * NHP;
  const float* abase = images + (size_t)(b * 3) * (IMG * IMG)
                              + (size_t)(ph * PSZ) * IMG + pw * PSZ;
  const bf16_t* brow = WpT + (size_t)(n0 + sr) * PDIM + sh * 16;
  const int wave = tid >> 6;
  const int lane = tid & 63;
  const int wm = (wave >> 1) << 6;
  const int wn = (wave & 1) << 6;
  const int lr = lane & 15;
  const int lk = (lane >> 4) << 3;
  f32x4 acc[4][4] = {};
  for (int ks = 0; ks < PDIM / 32; ++ks) {
    const int k0 = ks * 32;
    const int c  = k0 >> 8;
    const int ib = (k0 >> 4) & 15;
    const float* asrc = abase + (size_t)c * (IMG * IMG) + (ib + sh) * IMG;
    const float4 av0 = *(const float4*)(asrc + 0);
    const float4 av1 = *(const float4*)(asrc + 4);
    const float4 av2 = *(const float4*)(asrc + 8);
    const float4 av3 = *(const float4*)(asrc + 12);
    const uint4 bv0 = *(const uint4*)(brow + k0);
    const uint4 bv1 = *(const uint4*)(brow + k0 + 8);
    __syncthreads();
    bf16x8 a0, a1;
    a0[0] = (bf16_t)av0.x; a0[1] = (bf16_t)av0.y; a0[2] = (bf16_t)av0.z; a0[3] = (bf16_t)av0.w;
    a0[4] = (bf16_t)av1.x; a0[5] = (bf16_t)av1.y; a0[6] = (bf16_t)av1.z; a0[7] = (bf16_t)av1.w;
    a1[0] = (bf16_t)av2.x; a1[1] = (bf16_t)av2.y; a1[2] = (bf16_t)av2.z; a1[3] = (bf16_t)av2.w;
    a1[4] = (bf16_t)av3.x; a1[5] = (bf16_t)av3.y; a1[6] = (bf16_t)av3.z; a1[7] = (bf16_t)av3.w;
    *(bf16x8*)&As[sr][sh * 16]     = a0;
    *(bf16x8*)&As[sr][sh * 16 + 8] = a1;
    *(uint4*)&Bs[sr][sh * 16]      = bv0;
    *(uint4*)&Bs[sr][sh * 16 + 8]  = bv1;
    __syncthreads();
    bf16x8 af[4], bfr[4];
    #pragma unroll
    for (int i = 0; i < 4; ++i) af[i]  = *(const bf16x8*)&As[wm + i * 16 + lr][lk];
    #pragma unroll
    for (int j = 0; j < 4; ++j) bfr[j] = *(const bf16x8*)&Bs[wn + j * 16 + lr][lk];
    #pragma unroll
    for (int i = 0; i < 4; ++i)
      #pragma unroll
      for (int j = 0; j < 4; ++j)
        acc[i][j] = __builtin_amdgcn_mfma_f32_16x16x32_bf16(af[i], bfr[j], acc[i][j], 0, 0, 0);
  }
  const int colb = n0 + wn;
  #pragma unroll
  for (int i = 0; i < 4; ++i) {
    #pragma unroll
    for (int r = 0; r < 4; ++r) {
      const int mm = m0 + wm + i * 16 + ((lane >> 4) << 2) + r;
      const int pp = mm % NPATCH;
      const float* pe = pos_embed + (size_t)pp * DMODEL;
      bf16_t* orow = xout + (size_t)mm * DMODEL;
      #pragma unroll
      for (int j = 0; j < 4; ++j) {
        const int nn = colb + j * 16 + lr;
        orow[nn] = (bf16_t)(acc[i][j][r] + b_patch[nn] + pe[nn]);
      }
    }
  }
}

// ---------------------------------------------------------------------------
// coords_k0 (K1): per 16 rows (one wave), coords + K0 via MFMA.
//   D1 = mfma(A=Wcs[16dc][512k], B=x rows) -> lane (q4,lr): comps q4+r of row lr
//   q4=0: c0-3, q4=4: c4-7, q4=8: spinor -> K0 in-lane.
//   Weights read from GLOBAL (16 KB, L1-resident) — no LDS, no barriers.
//   Cbuf[row][12]: c[0..7], K0 at [8].
// ---------------------------------------------------------------------------
__global__ __launch_bounds__(64) void coords_k0(
    const bf16_t* __restrict__ x, const bf16_t* __restrict__ Wcsg,
    const float* __restrict__ b_coord, const float* __restrict__ b_spinor,
    float* __restrict__ Cbuf)
{
  const int lane = threadIdx.x;
  const int lr   = lane & 15;
  const int lk   = (lane >> 4) << 3;    // 0,8,16,24
  const int q4   = (lane >> 4) << 2;    // 0,4,8,12
  const int m0w  = blockIdx.x * 16;

  float bbv[4];
  #pragma unroll
  for (int r = 0; r < 4; ++r) {
    if (q4 == 0)      bbv[r] = b_coord[r];
    else if (q4 == 4) bbv[r] = b_coord[4 + r];
    else if (q4 == 8) bbv[r] = b_spinor[r];
    else              bbv[r] = 0.f;
  }

  const bf16_t* xrow = x + (size_t)(m0w + lr) * DMODEL + lk;
  const bf16_t* wrow = Wcsg + lr * DMODEL + lk;
  f32x4 acc1 = {0.f, 0.f, 0.f, 0.f};
  #pragma unroll
  for (int ks = 0; ks < 16; ++ks) {
    const bf16x8 bf = *(const bf16x8*)(xrow + ks * 32);
    const bf16x8 wf = *(const bf16x8*)(wrow + ks * 32);
    acc1 = __builtin_amdgcn_mfma_f32_16x16x32_bf16(wf, bf, acc1, 0, 0, 0);
  }

  float sv[4];
  #pragma unroll
  for (int r = 0; r < 4; ++r) sv[r] = acc1[r] + bbv[r];

  float* crow = Cbuf + (size_t)(m0w + lr) * 12;
  if (q4 == 8) {
    crow[8] = sv[0] * sv[0] + sv[1] * sv[1] + sv[2] * sv[2] + sv[3] * sv[3];
  } else if (q4 == 0 || q4 == 4) {
    f32x4 st = {sv[0], sv[1], sv[2], sv[3]};
    *(f32x4*)(crow + q4) = st;
  }
}

// ---------------------------------------------------------------------------
// embed_ln (K2): x = LN((c @ We + be) * K0 + x) * gamma + beta, in-place.
// One wave per row; lane owns n = lane*8..+8. We/be/gamma/beta staged in
// REGISTERS once per wave (f32). 784 blocks x 4 waves, 8 rows per wave.
// ---------------------------------------------------------------------------
__global__ __launch_bounds__(256) void embed_ln(
    bf16_t* __restrict__ x, const float* __restrict__ Cbuf,
    const float* __restrict__ We, const float* __restrict__ be,
    const float* __restrict__ gamma, const float* __restrict__ beta)
{
  const int w    = threadIdx.x >> 6;
  const int lane = threadIdx.x & 63;
  const int n0   = lane * 8;

  // stage weights in registers (per-lane n-slice)
  f32x4 wlo[8], whi[8];
  #pragma unroll
  for (int dc = 0; dc < 8; ++dc) {
    wlo[dc] = *(const f32x4*)&We[dc * DMODEL + n0];
    whi[dc] = *(const f32x4*)&We[dc * DMODEL + n0 + 4];
  }
  const f32x4 beL = *(const f32x4*)&be[n0];
  const f32x4 beH = *(const f32x4*)&be[n0 + 4];
  const f32x4 gL  = *(const f32x4*)&gamma[n0];
  const f32x4 gH  = *(const f32x4*)&gamma[n0 + 4];
  const f32x4 btL = *(const f32x4*)&beta[n0];
  const f32x4 btH = *(const f32x4*)&beta[n0 + 4];

  const size_t base = (size_t)blockIdx.x * 32 + w * 8;
  #pragma unroll 2
  for (int rr = 0; rr < 8; ++rr) {
    const size_t row = base + rr;
    const bf16x8 xv = *(const bf16x8*)(x + row * DMODEL + n0);
    const float* crow = Cbuf + row * 12;
    const f32x4 c0 = *(const f32x4*)(crow);
    const f32x4 c1 = *(const f32x4*)(crow + 4);
    const float k0 = crow[8];

    float v[8];
    float s1 = 0.f, s2 = 0.f;
    #pragma unroll
    for (int e = 0; e < 4; ++e) {
      float xm = beL[e];
      #pragma unroll
      for (int dc = 0; dc < 4; ++dc) xm += c0[dc] * wlo[dc][e];
      #pragma unroll
      for (int dc = 0; dc < 4; ++dc) xm += c1[dc] * wlo[4 + dc][e];
      const float vv = xm * k0 + (float)xv[e];
      v[e] = vv; s1 += vv; s2 += vv * vv;
    }
    #pragma unroll
    for (int e = 0; e < 4; ++e) {
      float xm = beH[e];
      #pragma unroll
      for (int dc = 0; dc < 4; ++dc) xm += c0[dc] * whi[dc][e];
      #pragma unroll
      for (int dc = 0; dc < 4; ++dc) xm += c1[dc] * whi[4 + dc][e];
      const float vv = xm * k0 + (float)xv[4 + e];
      v[4 + e] = vv; s1 += vv; s2 += vv * vv;
    }

    #pragma unroll
    for (int off = 1; off <= 32; off <<= 1) {
      s1 += __shfl_xor(s1, off, 64);
      s2 += __shfl_xor(s2, off, 64);
    }
    const float mu  = s1 * (1.f / 512.f);
    const float var = s2 * (1.f / 512.f) - mu * mu;
    const float rs  = rsqrtf(var + 1e-5f);

    bf16x8 o;
    #pragma unroll
    for (int e = 0; e < 4; ++e) {
      o[e]     = (bf16_t)((v[e]     - mu) * rs * gL[e] + btL[e]);
      o[4 + e] = (bf16_t)((v[4 + e] - mu) * rs * gH[e] + btH[e]);
    }
    *(bf16x8*)(x + row * DMODEL + n0) = o;
  }
}

// ---------------------------------------------------------------------------
extern "C" void kernel_launch(void* const* d_in, const int* in_sizes, int n_in,
                              void* d_out, int out_size, void* d_ws, size_t ws_size,
                              hipStream_t stream)
{
  const float* images    = (const float*)d_in[0];
  const float* W_patch   = (const float*)d_in[1];
  const float* b_patch   = (const float*)d_in[2];
  const float* pos_embed = (const float*)d_in[3];
  const float* W_coord   = (const float*)d_in[4];
  const float* b_coord   = (const float*)d_in[5];
  const float* W_spinor  = (const float*)d_in[6];
  const float* b_spinor  = (const float*)d_in[7];
  const float* W_embed   = (const float*)d_in[8];
  const float* b_embed   = (const float*)d_in[9];
  const float* ln_gamma  = (const float*)d_in[10];
  const float* ln_beta   = (const float*)d_in[11];
  const float* W_out     = (const float*)d_in[12];
  const float* b_out     = (const float*)d_in[13];
  float* out = (float*)d_out;

  const size_t SZ_APAT = (size_t)MROWS * PDIM * 2;     // 38,535,168
  const size_t SZ_X    = (size_t)MROWS * DMODEL * 2;   // 25,690,112
  const size_t SZ_WPT  = (size_t)DMODEL * PDIM * 2;    //    786,432
  const size_t SZ_WOT  = (size_t)DMODEL * DMODEL * 2;  //    524,288
  const size_t SZ_WCS  = 16 * 512 * 2;                 //     16,384
  const size_t SZ_CBUF = (size_t)MROWS * 12 * 4;       //  1,204,224
  const size_t NEED_FULL = SZ_APAT + SZ_X + SZ_WPT + SZ_WOT + SZ_WCS + SZ_CBUF;

  char* ws = (char*)d_ws;
  const bool full = (ws_size >= NEED_FULL);

  bf16_t *Apat, *x, *WpT, *WoT, *Wcsg;
  float *Cbuf;
  if (full) {
    char* p = ws;
    Apat  = (bf16_t*)p;            p += SZ_APAT;
    x     = (bf16_t*)p;            p += SZ_X;
    WpT   = (bf16_t*)p;            p += SZ_WPT;
    WoT   = (bf16_t*)p;            p += SZ_WOT;
    Wcsg  = (bf16_t*)p;            p += SZ_WCS;
    Cbuf  = (float*)p;
  } else {
    char* p = ws;
    Apat  = nullptr;
    x     = (bf16_t*)p;            p += SZ_X;
    WpT   = (bf16_t*)p;            p += SZ_WPT;
    WoT   = (bf16_t*)p;            p += SZ_WOT;
    Wcsg  = (bf16_t*)p;            p += SZ_WCS;
    Cbuf  = (float*)p;
  }

  hipLaunchKernelGGL(transpose_to_bf16, dim3(8, 12), dim3(64, 4), 0, stream,
                     W_patch, WpT, PDIM, DMODEL);
  hipLaunchKernelGGL(transpose_to_bf16, dim3(8, 8), dim3(64, 4), 0, stream,
                     W_out, WoT, DMODEL, DMODEL);
  hipLaunchKernelGGL(manifold_prep, dim3(32), dim3(256), 0, stream,
                     W_coord, W_spinor, Wcsg);

  if (full) {
    hipLaunchKernelGGL(patchify_bf16, dim3(32 * 3 * 28), dim3(256), 0, stream,
                       images, Apat);
    hipLaunchKernelGGL((gemm_bf16<PDIM, 0>), dim3(1568), dim3(256), 0, stream,
                       Apat, WpT, b_patch, pos_embed, (void*)x);
  } else {
    hipLaunchKernelGGL(gemm1_fused_fallback, dim3(4, 196), dim3(256), 0, stream,
                       images, WpT, b_patch, pos_embed, x);
  }

  hipLaunchKernelGGL(coords_k0, dim3(MROWS / 16), dim3(64), 0, stream,
                     x, Wcsg, b_coord, b_spinor, Cbuf);
  hipLaunchKernelGGL(embed_ln, dim3(MROWS / 32), dim3(256), 0, stream,
                     x, Cbuf, W_embed, b_embed, ln_gamma, ln_beta);

  hipLaunchKernelGGL((gemm_bf16<DMODEL, 1>), dim3(1568), dim3(256), 0, stream,
                     x, WoT, b_out, (const float*)nullptr, (void*)out);
}